// Round 3
// baseline (352.041 us; speedup 1.0000x reference)
//
#include <hip/hip_runtime.h>

typedef _Float16 h16;
typedef __attribute__((ext_vector_type(2))) _Float16 half2v;
typedef __attribute__((ext_vector_type(4))) _Float16 half4;
typedef __attribute__((ext_vector_type(8))) _Float16 half8;
typedef __attribute__((ext_vector_type(4))) float f32x4;

#define Cn 8
#define HWn 65536
#define CHWn 524288

// ================================================================ FAST PATH
// ---------------------------------------------------------------- K1: prep (v2, R2-proven)
// Block = [32 j x 32 w] tile, grid (8 wt, 8 jt, 64 b). Thread strip = 1 j x 4 w:
// 8 independent float4 loads, FMA chain, single barrier, LDS transpose for vt.
// Outputs: qh,kh fp16 [b][h][w]; vt fp16 [b][c][w][j] with b3 folded.
#define PADW 42
__global__ __launch_bounds__(256) void prep_kernel(
    const float* __restrict__ x, const float* __restrict__ w1, const float* __restrict__ b1,
    const float* __restrict__ w2, const float* __restrict__ b2,
    const float* __restrict__ w3, const float* __restrict__ b3,
    h16* __restrict__ qh, h16* __restrict__ kh, h16* __restrict__ vt) {
  const int wt = blockIdx.x, jt = blockIdx.y, b = blockIdx.z;
  const int j0 = jt * 32, w0 = wt * 32;
  const int t = threadIdx.x;
  const int jl = t >> 3, wq = t & 7;
  __shared__ h16 sv[8 * 32 * PADW];

  float4 xv[8];
  const float* xb = x + ((size_t)b << 19) + (size_t)(j0 + jl) * 256 + w0 + wq * 4;
#pragma unroll
  for (int ci = 0; ci < 8; ci++)
    xv[ci] = *(const float4*)(xb + ((size_t)ci << 16));

  float qa[4], ka[4], va[8][4];
  const float bb1 = b1[0], bb2 = b2[0];
#pragma unroll
  for (int e = 0; e < 4; e++) { qa[e] = bb1; ka[e] = bb2; }
#pragma unroll
  for (int co = 0; co < 8; co++) {
    const float bv = b3[co];
#pragma unroll
    for (int e = 0; e < 4; e++) va[co][e] = bv;
  }
#pragma unroll
  for (int ci = 0; ci < 8; ci++) {
    const float xe[4] = {xv[ci].x, xv[ci].y, xv[ci].z, xv[ci].w};
    const float w1c = w1[ci], w2c = w2[ci];
#pragma unroll
    for (int e = 0; e < 4; e++) {
      qa[e] = fmaf(xe[e], w1c, qa[e]);
      ka[e] = fmaf(xe[e], w2c, ka[e]);
    }
#pragma unroll
    for (int co = 0; co < 8; co++) {
      const float w3c = w3[co * 8 + ci];
#pragma unroll
      for (int e = 0; e < 4; e++) va[co][e] = fmaf(xe[e], w3c, va[co][e]);
    }
  }

  {
    half4 qv = {(h16)qa[0], (h16)qa[1], (h16)qa[2], (h16)qa[3]};
    half4 kv = {(h16)ka[0], (h16)ka[1], (h16)ka[2], (h16)ka[3]};
    size_t off = ((size_t)b << 16) + (size_t)(j0 + jl) * 256 + w0 + wq * 4;
    *(half4*)&qh[off] = qv;
    *(half4*)&kh[off] = kv;
  }

#pragma unroll
  for (int co = 0; co < 8; co++) {
    half2v v01 = {(h16)va[co][0], (h16)va[co][1]};
    half2v v23 = {(h16)va[co][2], (h16)va[co][3]};
    h16* p = &sv[co * 32 * PADW + jl * PADW + wq * 4];
    *(half2v*)p = v01;
    *(half2v*)(p + 2) = v23;
  }
  __syncthreads();

#pragma unroll
  for (int cc = 0; cc < 4; cc++) {
    const int cid = t + 256 * cc;
    const int co = cid >> 7;
    const int w = (cid >> 2) & 31;
    const int jc = cid & 3;
    const h16* rp = &sv[co * 32 * PADW + (jc * 8) * PADW + w];
    half8 pk;
#pragma unroll
    for (int e = 0; e < 8; e++) pk[e] = rp[e * PADW];
    *(half8*)&vt[((size_t)(b * Cn + co) * 256 + w0 + w) * 256 + j0 + jc * 8] = pk;
  }
}

// ---------------------------------------------------------------- K2: fused scores+softmax+apply
// Grid (4 it, 64 b), 512 threads = 8 waves. Per block: 64 i-rows, full j=256, full n=2048.
// Phase A: wave (iw=wv>>1, jw=wv&1) computes QK^T 16i x 128j via mfma(K,Q)
//   (lane: col i = m, row j = jw*128 + jt*16 + quad*4 + r). 2-wave softmax reduce.
//   P (fp16) -> LDS Ps[64][264] (stride 264 halfs = 528B: 16B-aligned rows).
// Phase B: per wave, hoist ALL A-frags to regs (afr[8 kc][4 ai], 128 VGPR, static
//   indices only), then sweep 16 n-tiles reading B-frags DIRECTLY from global vt
//   (L3-resident, written by prep this iteration). Zero barriers / LDS in main GEMM.
__global__ __launch_bounds__(512, 2) void fused_sa(
    const h16* __restrict__ qh, const h16* __restrict__ kh,
    const h16* __restrict__ vt, float* __restrict__ out) {
  const int it = blockIdx.x, b = blockIdx.y;
  const int t = threadIdx.x, wv = t >> 6, lane = t & 63;
  const int m = lane & 15, quad = lane >> 4;
  const int iw = wv >> 1, jw = wv & 1;
  __shared__ h16 Ps[64 * 264];
  __shared__ float red[2][8][16];

  // ---- phase A: QK^T
  const h16* qrow = qh + ((size_t)b << 16) + (size_t)(it * 64 + iw * 16 + m) * 256 + quad * 8;
  const h16* kbase = kh + ((size_t)b << 16) + (size_t)(jw * 128 + m) * 256 + quad * 8;
  f32x4 acc[8];
#pragma unroll
  for (int jt = 0; jt < 8; jt++) acc[jt] = {0.f, 0.f, 0.f, 0.f};
#pragma unroll
  for (int s = 0; s < 8; s++) {
    half8 Q = *(const half8*)(qrow + s * 32);
#pragma unroll
    for (int jt = 0; jt < 8; jt++) {
      half8 K = *(const half8*)(kbase + jt * 4096 + s * 32);
      acc[jt] = __builtin_amdgcn_mfma_f32_16x16x32_f16(K, Q, acc[jt], 0, 0, 0);
    }
  }
  // ---- softmax (row i = m; wave holds 128 j; pair waves {iw*2, iw*2+1})
  float mx = -3.4e38f;
#pragma unroll
  for (int jt = 0; jt < 8; jt++)
#pragma unroll
    for (int r = 0; r < 4; r++) mx = fmaxf(mx, acc[jt][r]);
  mx = fmaxf(mx, __shfl_xor(mx, 16, 64));
  mx = fmaxf(mx, __shfl_xor(mx, 32, 64));
  if (lane < 16) red[0][wv][lane] = mx;
  __syncthreads();
  const float gmx = fmaxf(red[0][iw * 2][m], red[0][iw * 2 + 1][m]);
  float sum = 0.f;
#pragma unroll
  for (int jt = 0; jt < 8; jt++)
#pragma unroll
    for (int r = 0; r < 4; r++) {
      float e = __expf(acc[jt][r] - gmx);
      acc[jt][r] = e;
      sum += e;
    }
  sum += __shfl_xor(sum, 16, 64);
  sum += __shfl_xor(sum, 32, 64);
  if (lane < 16) red[1][wv][lane] = sum;
  __syncthreads();
  const float inv = 1.f / (red[1][iw * 2][m] + red[1][iw * 2 + 1][m]);
#pragma unroll
  for (int jt = 0; jt < 8; jt++) {
    half4 pv = {(h16)(acc[jt][0] * inv), (h16)(acc[jt][1] * inv),
                (h16)(acc[jt][2] * inv), (h16)(acc[jt][3] * inv)};
    *(half4*)&Ps[(iw * 16 + m) * 264 + jw * 128 + jt * 16 + quad * 4] = pv;
  }
  __syncthreads();

  // ---- phase B: out[64 i x 2048 n] = P * vt^T, wave owns 16 n per 128-n tile
  half8 afr[8][4];
#pragma unroll
  for (int kc = 0; kc < 8; kc++)
#pragma unroll
    for (int ai = 0; ai < 4; ai++)
      afr[kc][ai] = *(const half8*)&Ps[(ai * 16 + m) * 264 + kc * 32 + quad * 8];

  for (int nt = 0; nt < 16; nt++) {
    const int c = nt >> 1;
    const int wloc = (nt & 1) * 128 + wv * 16 + m;
    const h16* vrow = vt + ((size_t)((b * 8 + c) * 256 + wloc) << 8) + quad * 8;
    f32x4 a2[4];
#pragma unroll
    for (int ai = 0; ai < 4; ai++) a2[ai] = {0.f, 0.f, 0.f, 0.f};
#pragma unroll
    for (int kc = 0; kc < 8; kc++) {
      half8 bf = *(const half8*)(vrow + kc * 32);
#pragma unroll
      for (int ai = 0; ai < 4; ai++)
        a2[ai] = __builtin_amdgcn_mfma_f32_16x16x32_f16(afr[kc][ai], bf, a2[ai], 0, 0, 0);
    }
    float* ob = out + (((size_t)(b * 8 + c)) << 16) + (size_t)(it * 64 + quad * 4) * 256 + wloc;
#pragma unroll
    for (int ai = 0; ai < 4; ai++)
#pragma unroll
      for (int r = 0; r < 4; r++)
        ob[(size_t)(ai * 16 + r) * 256] = a2[ai][r];
  }
}

// ================================================================ FALLBACK (fp32, R1-proven)
__global__ __launch_bounds__(256) void qk_kernel(
    const float* __restrict__ x, const float* __restrict__ w1, const float* __restrict__ b1,
    const float* __restrict__ w2, const float* __restrict__ b2,
    float* __restrict__ q, float* __restrict__ k) {
  int n = blockIdx.x * 256 + threadIdx.x;
  int b = n >> 16;
  int pidx = n & 65535;
  const float* xb = x + (size_t)b * CHWn + pidx;
  float qa = b1[0], ka = b2[0];
#pragma unroll
  for (int c = 0; c < Cn; c++) {
    float xv = xb[c * HWn];
    qa = fmaf(xv, w1[c], qa);
    ka = fmaf(xv, w2[c], ka);
  }
  q[n] = qa;
  k[n] = ka;
}

__global__ __launch_bounds__(256) void scores_kernel_f32(
    const float* __restrict__ q, const float* __restrict__ k, float* __restrict__ sc) {
  const int jt = blockIdx.x, it = blockIdx.y, b = blockIdx.z;
  const int i0 = it * 128, j0 = jt * 128;
  const int t = threadIdx.x;
  const int tx = t & 15, ty = t >> 4;
  __shared__ __align__(16) float qt[32 * 132];
  __shared__ __align__(16) float kt[32 * 132];
  float acc[2][2][4][4];
#pragma unroll
  for (int a = 0; a < 2; a++)
#pragma unroll
    for (int bb = 0; bb < 2; bb++)
#pragma unroll
      for (int il = 0; il < 4; il++)
#pragma unroll
        for (int jl = 0; jl < 4; jl++) acc[a][bb][il][jl] = 0.f;
  const float* qb = q + (size_t)b * HWn;
  const float* kb = k + (size_t)b * HWn;
  for (int kc = 0; kc < 8; kc++) {
    const int w0 = kc * 32;
    __syncthreads();
#pragma unroll
    for (int e = 0; e < 16; e++) {
      int idx = t + 256 * e;
      int r = idx >> 5, c = idx & 31;
      qt[c * 132 + r] = qb[(i0 + r) * 256 + w0 + c];
      kt[c * 132 + r] = kb[(j0 + r) * 256 + w0 + c];
    }
    __syncthreads();
#pragma unroll 4
    for (int w = 0; w < 32; w++) {
      const float4 a0 = *(const float4*)&qt[w * 132 + ty * 4];
      const float4 a1 = *(const float4*)&qt[w * 132 + 64 + ty * 4];
      const float4 b0 = *(const float4*)&kt[w * 132 + tx * 4];
      const float4 b1 = *(const float4*)&kt[w * 132 + 64 + tx * 4];
      const float av[2][4] = {{a0.x, a0.y, a0.z, a0.w}, {a1.x, a1.y, a1.z, a1.w}};
      const float bv[2][4] = {{b0.x, b0.y, b0.z, b0.w}, {b1.x, b1.y, b1.z, b1.w}};
#pragma unroll
      for (int ih = 0; ih < 2; ih++)
#pragma unroll
        for (int jh = 0; jh < 2; jh++)
#pragma unroll
          for (int il = 0; il < 4; il++)
#pragma unroll
            for (int jl = 0; jl < 4; jl++)
              acc[ih][jh][il][jl] = fmaf(av[ih][il], bv[jh][jl], acc[ih][jh][il][jl]);
    }
  }
  float* scb = sc + (size_t)b * HWn;
#pragma unroll
  for (int ih = 0; ih < 2; ih++)
#pragma unroll
    for (int il = 0; il < 4; il++) {
      int i = i0 + ih * 64 + ty * 4 + il;
#pragma unroll
      for (int jh = 0; jh < 2; jh++) {
        float4 st = make_float4(acc[ih][jh][il][0], acc[ih][jh][il][1],
                                acc[ih][jh][il][2], acc[ih][jh][il][3]);
        *(float4*)&scb[i * 256 + j0 + jh * 64 + tx * 4] = st;
      }
    }
}

__global__ __launch_bounds__(256) void softmax_kernel(float* __restrict__ at) {
  int wave = (blockIdx.x * 256 + threadIdx.x) >> 6;
  int lane = threadIdx.x & 63;
  float* row = at + (size_t)wave * 256;
  float v[4];
  float mm = -3.4e38f;
#pragma unroll
  for (int u = 0; u < 4; u++) {
    v[u] = row[lane + 64 * u];
    mm = fmaxf(mm, v[u]);
  }
#pragma unroll
  for (int o = 1; o < 64; o <<= 1) mm = fmaxf(mm, __shfl_xor(mm, o, 64));
  float s = 0.f;
#pragma unroll
  for (int u = 0; u < 4; u++) {
    v[u] = __expf(v[u] - mm);
    s += v[u];
  }
#pragma unroll
  for (int o = 1; o < 64; o <<= 1) s += __shfl_xor(s, o, 64);
  float inv = 1.0f / s;
#pragma unroll
  for (int u = 0; u < 4; u++) row[lane + 64 * u] = v[u] * inv;
}

__global__ __launch_bounds__(256, 2) void apply_kernel(
    const float* __restrict__ x, const float* __restrict__ at,
    const float* __restrict__ w3, const float* __restrict__ b3, float* __restrict__ out) {
  const int it = blockIdx.x, b = blockIdx.y;
  const int i0 = it * 16;
  const int t = threadIdx.x;
  __shared__ __align__(16) float pt[16 * 256];
  const float* atb = at + (size_t)b * HWn + i0 * 256;
#pragma unroll
  for (int e = 0; e < 4; e++)
    *(float4*)&pt[t * 4 + 1024 * e] = *(const float4*)&atb[t * 4 + 1024 * e];
  __syncthreads();
  float acc[8][16];
#pragma unroll
  for (int c = 0; c < 8; c++)
#pragma unroll
    for (int ii = 0; ii < 16; ii++) acc[c][ii] = 0.f;
  const float* xb = x + (size_t)b * CHWn + t;
  for (int j0 = 0; j0 < 256; j0 += 2) {
    float p2[16][2];
#pragma unroll
    for (int ii = 0; ii < 16; ii++) {
      float2 pp = *(const float2*)&pt[ii * 256 + j0];
      p2[ii][0] = pp.x;
      p2[ii][1] = pp.y;
    }
#pragma unroll
    for (int ju = 0; ju < 2; ju++) {
      float xv[8];
#pragma unroll
      for (int c = 0; c < 8; c++) xv[c] = xb[c * HWn + (j0 + ju) * 256];
#pragma unroll
      for (int c = 0; c < 8; c++)
#pragma unroll
        for (int ii = 0; ii < 16; ii++)
          acc[c][ii] = fmaf(xv[c], p2[ii][ju], acc[c][ii]);
    }
  }
#pragma unroll
  for (int co = 0; co < 8; co++) {
    float wr[8];
#pragma unroll
    for (int ci = 0; ci < 8; ci++) wr[ci] = w3[co * 8 + ci];
    float bb = b3[co];
#pragma unroll
    for (int ii = 0; ii < 16; ii++) {
      float o = bb;
#pragma unroll
      for (int ci = 0; ci < 8; ci++) o = fmaf(wr[ci], acc[ci][ii], o);
      out[(size_t)b * CHWn + co * HWn + (i0 + ii) * 256 + t] = o;
    }
  }
}

extern "C" void kernel_launch(void* const* d_in, const int* in_sizes, int n_in,
                              void* d_out, int out_size, void* d_ws, size_t ws_size,
                              hipStream_t stream) {
  const float* x  = (const float*)d_in[0];
  const float* w1 = (const float*)d_in[1];
  const float* b1 = (const float*)d_in[2];
  const float* w2 = (const float*)d_in[3];
  const float* b2 = (const float*)d_in[4];
  const float* w3 = (const float*)d_in[5];
  const float* b3 = (const float*)d_in[6];
  float* out = (float*)d_out;

  if (ws_size >= (size_t)92274688) {
    // fast path: vt 64MB | qh 8MB | kh 8MB
    char* wsb = (char*)d_ws;
    h16* vt = (h16*)wsb;
    h16* qh = (h16*)(wsb + 67108864);
    h16* kh = (h16*)(wsb + 75497472);
    prep_kernel<<<dim3(8, 8, 64), dim3(256), 0, stream>>>(x, w1, b1, w2, b2, w3, b3, qh, kh, vt);
    fused_sa<<<dim3(4, 64), dim3(512), 0, stream>>>(qh, kh, vt, out);
  } else {
    float* wsf = (float*)d_ws;
    float* q  = wsf;
    float* k  = wsf + 4194304;
    float* at = wsf + 8388608;
    qk_kernel<<<dim3(16384), dim3(256), 0, stream>>>(x, w1, b1, w2, b2, q, k);
    scores_kernel_f32<<<dim3(2, 2, 64), dim3(256), 0, stream>>>(q, k, at);
    softmax_kernel<<<dim3(4096), dim3(256), 0, stream>>>(at);
    apply_kernel<<<dim3(16, 64), dim3(256), 0, stream>>>(x, at, w3, b3, out);
  }
}

// Round 4
// 338.864 us; speedup vs baseline: 1.0389x; 1.0389x over previous
//
#include <hip/hip_runtime.h>

typedef _Float16 h16;
typedef __attribute__((ext_vector_type(2))) _Float16 half2v;
typedef __attribute__((ext_vector_type(4))) _Float16 half4;
typedef __attribute__((ext_vector_type(8))) _Float16 half8;
typedef __attribute__((ext_vector_type(4))) float f32x4;

#define Cn 8
#define HWn 65536
#define CHWn 524288

// ================================================================ FAST PATH
// ---------------------------------------------------------------- K1: prep (v2, R2-proven)
// Block = [32 j x 32 w] tile, grid (8 wt, 8 jt, 64 b). Thread strip = 1 j x 4 w:
// 8 independent float4 loads, FMA chain, single barrier, LDS transpose for vt.
// Outputs: qh,kh fp16 [b][h][w]; vt fp16 [b][c][w][j] with b3 folded.
#define PADW 42
__global__ __launch_bounds__(256) void prep_kernel(
    const float* __restrict__ x, const float* __restrict__ w1, const float* __restrict__ b1,
    const float* __restrict__ w2, const float* __restrict__ b2,
    const float* __restrict__ w3, const float* __restrict__ b3,
    h16* __restrict__ qh, h16* __restrict__ kh, h16* __restrict__ vt) {
  const int wt = blockIdx.x, jt = blockIdx.y, b = blockIdx.z;
  const int j0 = jt * 32, w0 = wt * 32;
  const int t = threadIdx.x;
  const int jl = t >> 3, wq = t & 7;
  __shared__ h16 sv[8 * 32 * PADW];

  float4 xv[8];
  const float* xb = x + ((size_t)b << 19) + (size_t)(j0 + jl) * 256 + w0 + wq * 4;
#pragma unroll
  for (int ci = 0; ci < 8; ci++)
    xv[ci] = *(const float4*)(xb + ((size_t)ci << 16));

  float qa[4], ka[4], va[8][4];
  const float bb1 = b1[0], bb2 = b2[0];
#pragma unroll
  for (int e = 0; e < 4; e++) { qa[e] = bb1; ka[e] = bb2; }
#pragma unroll
  for (int co = 0; co < 8; co++) {
    const float bv = b3[co];
#pragma unroll
    for (int e = 0; e < 4; e++) va[co][e] = bv;
  }
#pragma unroll
  for (int ci = 0; ci < 8; ci++) {
    const float xe[4] = {xv[ci].x, xv[ci].y, xv[ci].z, xv[ci].w};
    const float w1c = w1[ci], w2c = w2[ci];
#pragma unroll
    for (int e = 0; e < 4; e++) {
      qa[e] = fmaf(xe[e], w1c, qa[e]);
      ka[e] = fmaf(xe[e], w2c, ka[e]);
    }
#pragma unroll
    for (int co = 0; co < 8; co++) {
      const float w3c = w3[co * 8 + ci];
#pragma unroll
      for (int e = 0; e < 4; e++) va[co][e] = fmaf(xe[e], w3c, va[co][e]);
    }
  }

  {
    half4 qv = {(h16)qa[0], (h16)qa[1], (h16)qa[2], (h16)qa[3]};
    half4 kv = {(h16)ka[0], (h16)ka[1], (h16)ka[2], (h16)ka[3]};
    size_t off = ((size_t)b << 16) + (size_t)(j0 + jl) * 256 + w0 + wq * 4;
    *(half4*)&qh[off] = qv;
    *(half4*)&kh[off] = kv;
  }

#pragma unroll
  for (int co = 0; co < 8; co++) {
    half2v v01 = {(h16)va[co][0], (h16)va[co][1]};
    half2v v23 = {(h16)va[co][2], (h16)va[co][3]};
    h16* p = &sv[co * 32 * PADW + jl * PADW + wq * 4];
    *(half2v*)p = v01;
    *(half2v*)(p + 2) = v23;
  }
  __syncthreads();

#pragma unroll
  for (int cc = 0; cc < 4; cc++) {
    const int cid = t + 256 * cc;
    const int co = cid >> 7;
    const int w = (cid >> 2) & 31;
    const int jc = cid & 3;
    const h16* rp = &sv[co * 32 * PADW + (jc * 8) * PADW + w];
    half8 pk;
#pragma unroll
    for (int e = 0; e < 8; e++) pk[e] = rp[e * PADW];
    *(half8*)&vt[((size_t)(b * Cn + co) * 256 + w0 + w) * 256 + j0 + jc * 8] = pk;
  }
}

// ---------------------------------------------------------------- K2: scores + softmax (R2-proven)
// Block = 16 i-rows; 4 waves split j (64 each). mfma(K,Q): lane holds col i=lane&15,
// rows j = jt*16 + quad*4 + r. Cross-wave softmax via LDS. P stored fp16 [b][i][j].
__global__ __launch_bounds__(256) void scores_kernel(
    const h16* __restrict__ qh, const h16* __restrict__ kh, h16* __restrict__ p) {
  const int i0 = blockIdx.x * 16, b = blockIdx.y;
  const int t = threadIdx.x, wv = t >> 6, lane = t & 63;
  const int m = lane & 15, quad = lane >> 4;
  __shared__ float red[2][4][16];
  const h16* qrow = qh + ((size_t)b << 16) + (size_t)(i0 + m) * 256 + quad * 8;
  const h16* kbase = kh + ((size_t)b << 16) + (size_t)(wv * 64 + m) * 256 + quad * 8;
  f32x4 acc[4];
#pragma unroll
  for (int jt = 0; jt < 4; jt++) acc[jt] = {0.f, 0.f, 0.f, 0.f};
#pragma unroll
  for (int s = 0; s < 8; s++) {
    half8 Q = *(const half8*)(qrow + s * 32);
#pragma unroll
    for (int jt = 0; jt < 4; jt++) {
      half8 K = *(const half8*)(kbase + (size_t)jt * 4096 + s * 32);
      acc[jt] = __builtin_amdgcn_mfma_f32_16x16x32_f16(K, Q, acc[jt], 0, 0, 0);
    }
  }
  float mx = -3.4e38f;
#pragma unroll
  for (int jt = 0; jt < 4; jt++)
#pragma unroll
    for (int r = 0; r < 4; r++) mx = fmaxf(mx, acc[jt][r]);
  mx = fmaxf(mx, __shfl_xor(mx, 16, 64));
  mx = fmaxf(mx, __shfl_xor(mx, 32, 64));
  if (lane < 16) red[0][wv][lane] = mx;
  __syncthreads();
  float gmx = fmaxf(fmaxf(red[0][0][m], red[0][1][m]), fmaxf(red[0][2][m], red[0][3][m]));
  float sum = 0.f;
#pragma unroll
  for (int jt = 0; jt < 4; jt++)
#pragma unroll
    for (int r = 0; r < 4; r++) {
      float e = __expf(acc[jt][r] - gmx);
      acc[jt][r] = e;
      sum += e;
    }
  sum += __shfl_xor(sum, 16, 64);
  sum += __shfl_xor(sum, 32, 64);
  if (lane < 16) red[1][wv][lane] = sum;
  __syncthreads();
  const float inv = 1.f / (red[1][0][m] + red[1][1][m] + red[1][2][m] + red[1][3][m]);
  h16* pb = p + ((size_t)b << 16) + (size_t)(i0 + m) * 256;
#pragma unroll
  for (int jt = 0; jt < 4; jt++) {
    half4 pv = {(h16)(acc[jt][0] * inv), (h16)(acc[jt][1] * inv),
                (h16)(acc[jt][2] * inv), (h16)(acc[jt][3] * inv)};
    *(half4*)&pb[wv * 64 + jt * 16 + quad * 4] = pv;
  }
}

// ---------------------------------------------------------------- K3: apply v2 (vt-stationary)
// Grid (32 nb, 64 b), 512 thr = 8 waves. Block owns vt slab [64 w][256 j] of
// (b, c = nb>>2, w0 = (nb&3)*64): loaded to LDS ONCE (1 barrier total, pad 264
// -> <=2-way). Then full K=256 sweep: A-frags read directly from global p
// (p[b]=128KB, L2-hot, 32 co-resident blocks share). Zero vt re-reads from HBM,
// zero barriers/staging in main loop. Wave (iw=wv>>1, nw=wv&1) = 64i x 32n,
// acc[4][2]. Same fragment/epilogue mapping as R2-proven apply.
__global__ __launch_bounds__(512, 4) void apply_kernel_v2(
    const h16* __restrict__ p, const h16* __restrict__ vt, float* __restrict__ out) {
  const int nb = blockIdx.x, b = blockIdx.y;
  const int c = nb >> 2, w0 = (nb & 3) * 64;
  const int t = threadIdx.x, wv = t >> 6, lane = t & 63;
  const int m = lane & 15, quad = lane >> 4;
  const int iw = wv >> 1, nw = wv & 1;
  __shared__ h16 Bs[64 * 264];

  // cooperative one-shot load: vt slab 64 rows x 512B, coalesced
  const h16* vbase = vt + (((size_t)(b * Cn + c) * 256 + w0) << 8);
#pragma unroll
  for (int e = 0; e < 4; e++) {
    const int idx = t + 512 * e;
    const int row = idx >> 5, ch = idx & 31;
    *(uint4*)&Bs[row * 264 + ch * 8] = *(const uint4*)&vbase[(size_t)row * 256 + ch * 8];
  }
  __syncthreads();

  const h16* gA = p + ((size_t)b << 16) + (size_t)(iw * 64 + m) * 256 + quad * 8;
  f32x4 acc[4][2];
#pragma unroll
  for (int ai = 0; ai < 4; ai++)
#pragma unroll
    for (int bi = 0; bi < 2; bi++) acc[ai][bi] = {0.f, 0.f, 0.f, 0.f};

#pragma unroll
  for (int kc = 0; kc < 8; kc++) {
    half8 af[4], bf[2];
#pragma unroll
    for (int ai = 0; ai < 4; ai++)
      af[ai] = *(const half8*)(gA + (size_t)ai * 4096 + kc * 32);
#pragma unroll
    for (int bi = 0; bi < 2; bi++)
      bf[bi] = *(const half8*)&Bs[(nw * 32 + bi * 16 + m) * 264 + kc * 32 + quad * 8];
#pragma unroll
    for (int ai = 0; ai < 4; ai++)
#pragma unroll
      for (int bi = 0; bi < 2; bi++)
        acc[ai][bi] = __builtin_amdgcn_mfma_f32_16x16x32_f16(af[ai], bf[bi], acc[ai][bi], 0, 0, 0);
  }

  float* ob = out + (((size_t)(b * Cn + c)) << 16) + w0 + nw * 32;
#pragma unroll
  for (int ai = 0; ai < 4; ai++) {
    const int ib = iw * 64 + ai * 16 + quad * 4;
#pragma unroll
    for (int r = 0; r < 4; r++)
#pragma unroll
      for (int bi = 0; bi < 2; bi++)
        ob[(size_t)(ib + r) * 256 + bi * 16 + m] = acc[ai][bi][r];
  }
}

// ================================================================ FALLBACK (fp32, R1-proven)
__global__ __launch_bounds__(256) void qk_kernel(
    const float* __restrict__ x, const float* __restrict__ w1, const float* __restrict__ b1,
    const float* __restrict__ w2, const float* __restrict__ b2,
    float* __restrict__ q, float* __restrict__ k) {
  int n = blockIdx.x * 256 + threadIdx.x;
  int b = n >> 16;
  int pidx = n & 65535;
  const float* xb = x + (size_t)b * CHWn + pidx;
  float qa = b1[0], ka = b2[0];
#pragma unroll
  for (int c = 0; c < Cn; c++) {
    float xv = xb[c * HWn];
    qa = fmaf(xv, w1[c], qa);
    ka = fmaf(xv, w2[c], ka);
  }
  q[n] = qa;
  k[n] = ka;
}

__global__ __launch_bounds__(256) void scores_kernel_f32(
    const float* __restrict__ q, const float* __restrict__ k, float* __restrict__ sc) {
  const int jt = blockIdx.x, it = blockIdx.y, b = blockIdx.z;
  const int i0 = it * 128, j0 = jt * 128;
  const int t = threadIdx.x;
  const int tx = t & 15, ty = t >> 4;
  __shared__ __align__(16) float qt[32 * 132];
  __shared__ __align__(16) float kt[32 * 132];
  float acc[2][2][4][4];
#pragma unroll
  for (int a = 0; a < 2; a++)
#pragma unroll
    for (int bb = 0; bb < 2; bb++)
#pragma unroll
      for (int il = 0; il < 4; il++)
#pragma unroll
        for (int jl = 0; jl < 4; jl++) acc[a][bb][il][jl] = 0.f;
  const float* qb = q + (size_t)b * HWn;
  const float* kb = k + (size_t)b * HWn;
  for (int kc = 0; kc < 8; kc++) {
    const int w0 = kc * 32;
    __syncthreads();
#pragma unroll
    for (int e = 0; e < 16; e++) {
      int idx = t + 256 * e;
      int r = idx >> 5, c = idx & 31;
      qt[c * 132 + r] = qb[(i0 + r) * 256 + w0 + c];
      kt[c * 132 + r] = kb[(j0 + r) * 256 + w0 + c];
    }
    __syncthreads();
#pragma unroll 4
    for (int w = 0; w < 32; w++) {
      const float4 a0 = *(const float4*)&qt[w * 132 + ty * 4];
      const float4 a1 = *(const float4*)&qt[w * 132 + 64 + ty * 4];
      const float4 b0 = *(const float4*)&kt[w * 132 + tx * 4];
      const float4 b1 = *(const float4*)&kt[w * 132 + 64 + tx * 4];
      const float av[2][4] = {{a0.x, a0.y, a0.z, a0.w}, {a1.x, a1.y, a1.z, a1.w}};
      const float bv[2][4] = {{b0.x, b0.y, b0.z, b0.w}, {b1.x, b1.y, b1.z, b1.w}};
#pragma unroll
      for (int ih = 0; ih < 2; ih++)
#pragma unroll
        for (int jh = 0; jh < 2; jh++)
#pragma unroll
          for (int il = 0; il < 4; il++)
#pragma unroll
            for (int jl = 0; jl < 4; jl++)
              acc[ih][jh][il][jl] = fmaf(av[ih][il], bv[jh][jl], acc[ih][jh][il][jl]);
    }
  }
  float* scb = sc + (size_t)b * HWn;
#pragma unroll
  for (int ih = 0; ih < 2; ih++)
#pragma unroll
    for (int il = 0; il < 4; il++) {
      int i = i0 + ih * 64 + ty * 4 + il;
#pragma unroll
      for (int jh = 0; jh < 2; jh++) {
        float4 st = make_float4(acc[ih][jh][il][0], acc[ih][jh][il][1],
                                acc[ih][jh][il][2], acc[ih][jh][il][3]);
        *(float4*)&scb[i * 256 + j0 + jh * 64 + tx * 4] = st;
      }
    }
}

__global__ __launch_bounds__(256) void softmax_kernel(float* __restrict__ at) {
  int wave = (blockIdx.x * 256 + threadIdx.x) >> 6;
  int lane = threadIdx.x & 63;
  float* row = at + (size_t)wave * 256;
  float v[4];
  float mm = -3.4e38f;
#pragma unroll
  for (int u = 0; u < 4; u++) {
    v[u] = row[lane + 64 * u];
    mm = fmaxf(mm, v[u]);
  }
#pragma unroll
  for (int o = 1; o < 64; o <<= 1) mm = fmaxf(mm, __shfl_xor(mm, o, 64));
  float s = 0.f;
#pragma unroll
  for (int u = 0; u < 4; u++) {
    v[u] = __expf(v[u] - mm);
    s += v[u];
  }
#pragma unroll
  for (int o = 1; o < 64; o <<= 1) s += __shfl_xor(s, o, 64);
  float inv = 1.0f / s;
#pragma unroll
  for (int u = 0; u < 4; u++) row[lane + 64 * u] = v[u] * inv;
}

__global__ __launch_bounds__(256, 2) void apply_kernel(
    const float* __restrict__ x, const float* __restrict__ at,
    const float* __restrict__ w3, const float* __restrict__ b3, float* __restrict__ out) {
  const int it = blockIdx.x, b = blockIdx.y;
  const int i0 = it * 16;
  const int t = threadIdx.x;
  __shared__ __align__(16) float pt[16 * 256];
  const float* atb = at + (size_t)b * HWn + i0 * 256;
#pragma unroll
  for (int e = 0; e < 4; e++)
    *(float4*)&pt[t * 4 + 1024 * e] = *(const float4*)&atb[t * 4 + 1024 * e];
  __syncthreads();
  float acc[8][16];
#pragma unroll
  for (int c = 0; c < 8; c++)
#pragma unroll
    for (int ii = 0; ii < 16; ii++) acc[c][ii] = 0.f;
  const float* xb = x + (size_t)b * CHWn + t;
  for (int j0 = 0; j0 < 256; j0 += 2) {
    float p2[16][2];
#pragma unroll
    for (int ii = 0; ii < 16; ii++) {
      float2 pp = *(const float2*)&pt[ii * 256 + j0];
      p2[ii][0] = pp.x;
      p2[ii][1] = pp.y;
    }
#pragma unroll
    for (int ju = 0; ju < 2; ju++) {
      float xv[8];
#pragma unroll
      for (int c = 0; c < 8; c++) xv[c] = xb[c * HWn + (j0 + ju) * 256];
#pragma unroll
      for (int c = 0; c < 8; c++)
#pragma unroll
        for (int ii = 0; ii < 16; ii++)
          acc[c][ii] = fmaf(xv[c], p2[ii][ju], acc[c][ii]);
    }
  }
#pragma unroll
  for (int co = 0; co < 8; co++) {
    float wr[8];
#pragma unroll
    for (int ci = 0; ci < 8; ci++) wr[ci] = w3[co * 8 + ci];
    float bb = b3[co];
#pragma unroll
    for (int ii = 0; ii < 16; ii++) {
      float o = bb;
#pragma unroll
      for (int ci = 0; ci < 8; ci++) o = fmaf(wr[ci], acc[ci][ii], o);
      out[(size_t)b * CHWn + co * HWn + (i0 + ii) * 256 + t] = o;
    }
  }
}

extern "C" void kernel_launch(void* const* d_in, const int* in_sizes, int n_in,
                              void* d_out, int out_size, void* d_ws, size_t ws_size,
                              hipStream_t stream) {
  const float* x  = (const float*)d_in[0];
  const float* w1 = (const float*)d_in[1];
  const float* b1 = (const float*)d_in[2];
  const float* w2 = (const float*)d_in[3];
  const float* b2 = (const float*)d_in[4];
  const float* w3 = (const float*)d_in[5];
  const float* b3 = (const float*)d_in[6];
  float* out = (float*)d_out;

  if (ws_size >= (size_t)92274688) {
    // fast path: vt 64MB | qh 8MB | kh 8MB | p 8MB
    char* wsb = (char*)d_ws;
    h16* vt = (h16*)wsb;
    h16* qh = (h16*)(wsb + 67108864);
    h16* kh = (h16*)(wsb + 75497472);
    h16* p  = (h16*)(wsb + 83886080);
    prep_kernel<<<dim3(8, 8, 64), dim3(256), 0, stream>>>(x, w1, b1, w2, b2, w3, b3, qh, kh, vt);
    scores_kernel<<<dim3(16, 64), dim3(256), 0, stream>>>(qh, kh, p);
    apply_kernel_v2<<<dim3(32, 64), dim3(512), 0, stream>>>(p, vt, out);
  } else {
    float* wsf = (float*)d_ws;
    float* q  = wsf;
    float* k  = wsf + 4194304;
    float* at = wsf + 8388608;
    qk_kernel<<<dim3(16384), dim3(256), 0, stream>>>(x, w1, b1, w2, b2, q, k);
    scores_kernel_f32<<<dim3(2, 2, 64), dim3(256), 0, stream>>>(q, k, at);
    softmax_kernel<<<dim3(4096), dim3(256), 0, stream>>>(at);
    apply_kernel<<<dim3(16, 64), dim3(256), 0, stream>>>(x, at, w3, b3, out);
  }
}

// Round 5
// 306.087 us; speedup vs baseline: 1.1501x; 1.1071x over previous
//
#include <hip/hip_runtime.h>

typedef _Float16 h16;
typedef __attribute__((ext_vector_type(2))) _Float16 half2v;
typedef __attribute__((ext_vector_type(4))) _Float16 half4;
typedef __attribute__((ext_vector_type(8))) _Float16 half8;
typedef __attribute__((ext_vector_type(4))) float f32x4;

#define Cn 8
#define HWn 65536
#define CHWn 524288

// ================================================================ FAST PATH
// ---------------------------------------------------------------- K1: prep (v2, R2-proven)
#define PADW 42
__global__ __launch_bounds__(256) void prep_kernel(
    const float* __restrict__ x, const float* __restrict__ w1, const float* __restrict__ b1,
    const float* __restrict__ w2, const float* __restrict__ b2,
    const float* __restrict__ w3, const float* __restrict__ b3,
    h16* __restrict__ qh, h16* __restrict__ kh, h16* __restrict__ vt) {
  const int wt = blockIdx.x, jt = blockIdx.y, b = blockIdx.z;
  const int j0 = jt * 32, w0 = wt * 32;
  const int t = threadIdx.x;
  const int jl = t >> 3, wq = t & 7;
  __shared__ h16 sv[8 * 32 * PADW];

  float4 xv[8];
  const float* xb = x + ((size_t)b << 19) + (size_t)(j0 + jl) * 256 + w0 + wq * 4;
#pragma unroll
  for (int ci = 0; ci < 8; ci++)
    xv[ci] = *(const float4*)(xb + ((size_t)ci << 16));

  float qa[4], ka[4], va[8][4];
  const float bb1 = b1[0], bb2 = b2[0];
#pragma unroll
  for (int e = 0; e < 4; e++) { qa[e] = bb1; ka[e] = bb2; }
#pragma unroll
  for (int co = 0; co < 8; co++) {
    const float bv = b3[co];
#pragma unroll
    for (int e = 0; e < 4; e++) va[co][e] = bv;
  }
#pragma unroll
  for (int ci = 0; ci < 8; ci++) {
    const float xe[4] = {xv[ci].x, xv[ci].y, xv[ci].z, xv[ci].w};
    const float w1c = w1[ci], w2c = w2[ci];
#pragma unroll
    for (int e = 0; e < 4; e++) {
      qa[e] = fmaf(xe[e], w1c, qa[e]);
      ka[e] = fmaf(xe[e], w2c, ka[e]);
    }
#pragma unroll
    for (int co = 0; co < 8; co++) {
      const float w3c = w3[co * 8 + ci];
#pragma unroll
      for (int e = 0; e < 4; e++) va[co][e] = fmaf(xe[e], w3c, va[co][e]);
    }
  }

  {
    half4 qv = {(h16)qa[0], (h16)qa[1], (h16)qa[2], (h16)qa[3]};
    half4 kv = {(h16)ka[0], (h16)ka[1], (h16)ka[2], (h16)ka[3]};
    size_t off = ((size_t)b << 16) + (size_t)(j0 + jl) * 256 + w0 + wq * 4;
    *(half4*)&qh[off] = qv;
    *(half4*)&kh[off] = kv;
  }

#pragma unroll
  for (int co = 0; co < 8; co++) {
    half2v v01 = {(h16)va[co][0], (h16)va[co][1]};
    half2v v23 = {(h16)va[co][2], (h16)va[co][3]};
    h16* p = &sv[co * 32 * PADW + jl * PADW + wq * 4];
    *(half2v*)p = v01;
    *(half2v*)(p + 2) = v23;
  }
  __syncthreads();

#pragma unroll
  for (int cc = 0; cc < 4; cc++) {
    const int cid = t + 256 * cc;
    const int co = cid >> 7;
    const int w = (cid >> 2) & 31;
    const int jc = cid & 3;
    const h16* rp = &sv[co * 32 * PADW + (jc * 8) * PADW + w];
    half8 pk;
#pragma unroll
    for (int e = 0; e < 8; e++) pk[e] = rp[e * PADW];
    *(half8*)&vt[((size_t)(b * Cn + co) * 256 + w0 + w) * 256 + j0 + jc * 8] = pk;
  }
}

// ---------------------------------------------------------------- K2: scores + softmax (R2-proven)
__global__ __launch_bounds__(256) void scores_kernel(
    const h16* __restrict__ qh, const h16* __restrict__ kh, h16* __restrict__ p) {
  const int i0 = blockIdx.x * 16, b = blockIdx.y;
  const int t = threadIdx.x, wv = t >> 6, lane = t & 63;
  const int m = lane & 15, quad = lane >> 4;
  __shared__ float red[2][4][16];
  const h16* qrow = qh + ((size_t)b << 16) + (size_t)(i0 + m) * 256 + quad * 8;
  const h16* kbase = kh + ((size_t)b << 16) + (size_t)(wv * 64 + m) * 256 + quad * 8;
  f32x4 acc[4];
#pragma unroll
  for (int jt = 0; jt < 4; jt++) acc[jt] = {0.f, 0.f, 0.f, 0.f};
#pragma unroll
  for (int s = 0; s < 8; s++) {
    half8 Q = *(const half8*)(qrow + s * 32);
#pragma unroll
    for (int jt = 0; jt < 4; jt++) {
      half8 K = *(const half8*)(kbase + (size_t)jt * 4096 + s * 32);
      acc[jt] = __builtin_amdgcn_mfma_f32_16x16x32_f16(K, Q, acc[jt], 0, 0, 0);
    }
  }
  float mx = -3.4e38f;
#pragma unroll
  for (int jt = 0; jt < 4; jt++)
#pragma unroll
    for (int r = 0; r < 4; r++) mx = fmaxf(mx, acc[jt][r]);
  mx = fmaxf(mx, __shfl_xor(mx, 16, 64));
  mx = fmaxf(mx, __shfl_xor(mx, 32, 64));
  if (lane < 16) red[0][wv][lane] = mx;
  __syncthreads();
  float gmx = fmaxf(fmaxf(red[0][0][m], red[0][1][m]), fmaxf(red[0][2][m], red[0][3][m]));
  float sum = 0.f;
#pragma unroll
  for (int jt = 0; jt < 4; jt++)
#pragma unroll
    for (int r = 0; r < 4; r++) {
      float e = __expf(acc[jt][r] - gmx);
      acc[jt][r] = e;
      sum += e;
    }
  sum += __shfl_xor(sum, 16, 64);
  sum += __shfl_xor(sum, 32, 64);
  if (lane < 16) red[1][wv][lane] = sum;
  __syncthreads();
  const float inv = 1.f / (red[1][0][m] + red[1][1][m] + red[1][2][m] + red[1][3][m]);
  h16* pb = p + ((size_t)b << 16) + (size_t)(i0 + m) * 256;
#pragma unroll
  for (int jt = 0; jt < 4; jt++) {
    half4 pv = {(h16)(acc[jt][0] * inv), (h16)(acc[jt][1] * inv),
                (h16)(acc[jt][2] * inv), (h16)(acc[jt][3] * inv)};
    *(half4*)&pb[wv * 64 + jt * 16 + quad * 4] = pv;
  }
}

// ---------------------------------------------------------------- K3: apply v3 (BM=256, vt read ONCE)
// v1's proven structure (LDS staging stride 40, uint4 register prefetch across
// barrier, 4 waves, acc[4][4], same fragment/epilogue mapping) with block tile
// 256i x 64n: grid (32 nb, 64 b), nb -> (c = nb>>2, w0 = (nb&3)*64). Each vt
// row is read by exactly ONE block (FETCH: vt 137->64 MB); p[b] (128KB) is
// shared via L2/L3 by the 32 blocks of b. Per kc: stage A 256x32 (4 chunks/thr)
// + B 64x32 (1 chunk/thr), 16 MFMA/wave. LDS 25.6 KB, 256 threads.
__global__ __launch_bounds__(256) void apply_kernel_v3(
    const h16* __restrict__ p, const h16* __restrict__ vt, float* __restrict__ out) {
  const int nb = blockIdx.x, b = blockIdx.y;
  const int c = nb >> 2, w0 = (nb & 3) * 64;
  const int t = threadIdx.x, wv = t >> 6, lane = t & 63;
  const int m = lane & 15, quad = lane >> 4;
  __shared__ h16 As[256 * 40];
  __shared__ h16 Bs[64 * 40];
  const int srow = t >> 2, soff = (t & 3) * 8;   // srow 0..63
  const h16* gA = p + ((size_t)b << 16) + (size_t)srow * 256 + soff;
  const h16* gB = vt + ((size_t)((b * Cn + c) * 256 + w0 + srow)) * 256 + soff;
  uint4 ra0 = *(const uint4*)gA;
  uint4 ra1 = *(const uint4*)(gA + 64 * 256);
  uint4 ra2 = *(const uint4*)(gA + 128 * 256);
  uint4 ra3 = *(const uint4*)(gA + 192 * 256);
  uint4 rb0 = *(const uint4*)gB;
  f32x4 acc[4][4];
#pragma unroll
  for (int ai = 0; ai < 4; ai++)
#pragma unroll
    for (int bi = 0; bi < 4; bi++) acc[ai][bi] = {0.f, 0.f, 0.f, 0.f};
  const int lA = srow * 40 + soff;
  for (int kc = 0; kc < 8; kc++) {
    __syncthreads();
    *(uint4*)&As[lA] = ra0;
    *(uint4*)&As[lA + 64 * 40] = ra1;
    *(uint4*)&As[lA + 128 * 40] = ra2;
    *(uint4*)&As[lA + 192 * 40] = ra3;
    *(uint4*)&Bs[lA] = rb0;
    __syncthreads();
    if (kc < 7) {
      const int ko = (kc + 1) * 32;
      ra0 = *(const uint4*)(gA + ko);
      ra1 = *(const uint4*)(gA + 64 * 256 + ko);
      ra2 = *(const uint4*)(gA + 128 * 256 + ko);
      ra3 = *(const uint4*)(gA + 192 * 256 + ko);
      rb0 = *(const uint4*)(gB + ko);
    }
    half8 af[4], bf[4];
#pragma unroll
    for (int ai = 0; ai < 4; ai++)
      af[ai] = *(const half8*)&As[(wv * 64 + ai * 16 + m) * 40 + quad * 8];
#pragma unroll
    for (int bi = 0; bi < 4; bi++)
      bf[bi] = *(const half8*)&Bs[(bi * 16 + m) * 40 + quad * 8];
#pragma unroll
    for (int ai = 0; ai < 4; ai++)
#pragma unroll
      for (int bi = 0; bi < 4; bi++)
        acc[ai][bi] = __builtin_amdgcn_mfma_f32_16x16x32_f16(af[ai], bf[bi], acc[ai][bi], 0, 0, 0);
  }
  float* ob = out + ((size_t)(b * Cn + c) << 16) + w0;
#pragma unroll
  for (int ai = 0; ai < 4; ai++) {
    const int ib = wv * 64 + ai * 16 + quad * 4;
#pragma unroll
    for (int r = 0; r < 4; r++)
#pragma unroll
      for (int bi = 0; bi < 4; bi++)
        ob[(size_t)(ib + r) * 256 + bi * 16 + m] = acc[ai][bi][r];
  }
}

// ================================================================ FALLBACK (fp32, R1-proven)
__global__ __launch_bounds__(256) void qk_kernel(
    const float* __restrict__ x, const float* __restrict__ w1, const float* __restrict__ b1,
    const float* __restrict__ w2, const float* __restrict__ b2,
    float* __restrict__ q, float* __restrict__ k) {
  int n = blockIdx.x * 256 + threadIdx.x;
  int b = n >> 16;
  int pidx = n & 65535;
  const float* xb = x + (size_t)b * CHWn + pidx;
  float qa = b1[0], ka = b2[0];
#pragma unroll
  for (int c = 0; c < Cn; c++) {
    float xv = xb[c * HWn];
    qa = fmaf(xv, w1[c], qa);
    ka = fmaf(xv, w2[c], ka);
  }
  q[n] = qa;
  k[n] = ka;
}

__global__ __launch_bounds__(256) void scores_kernel_f32(
    const float* __restrict__ q, const float* __restrict__ k, float* __restrict__ sc) {
  const int jt = blockIdx.x, it = blockIdx.y, b = blockIdx.z;
  const int i0 = it * 128, j0 = jt * 128;
  const int t = threadIdx.x;
  const int tx = t & 15, ty = t >> 4;
  __shared__ __align__(16) float qt[32 * 132];
  __shared__ __align__(16) float kt[32 * 132];
  float acc[2][2][4][4];
#pragma unroll
  for (int a = 0; a < 2; a++)
#pragma unroll
    for (int bb = 0; bb < 2; bb++)
#pragma unroll
      for (int il = 0; il < 4; il++)
#pragma unroll
        for (int jl = 0; jl < 4; jl++) acc[a][bb][il][jl] = 0.f;
  const float* qb = q + (size_t)b * HWn;
  const float* kb = k + (size_t)b * HWn;
  for (int kc = 0; kc < 8; kc++) {
    const int w0 = kc * 32;
    __syncthreads();
#pragma unroll
    for (int e = 0; e < 16; e++) {
      int idx = t + 256 * e;
      int r = idx >> 5, c = idx & 31;
      qt[c * 132 + r] = qb[(i0 + r) * 256 + w0 + c];
      kt[c * 132 + r] = kb[(j0 + r) * 256 + w0 + c];
    }
    __syncthreads();
#pragma unroll 4
    for (int w = 0; w < 32; w++) {
      const float4 a0 = *(const float4*)&qt[w * 132 + ty * 4];
      const float4 a1 = *(const float4*)&qt[w * 132 + 64 + ty * 4];
      const float4 b0 = *(const float4*)&kt[w * 132 + tx * 4];
      const float4 b1 = *(const float4*)&kt[w * 132 + 64 + tx * 4];
      const float av[2][4] = {{a0.x, a0.y, a0.z, a0.w}, {a1.x, a1.y, a1.z, a1.w}};
      const float bv[2][4] = {{b0.x, b0.y, b0.z, b0.w}, {b1.x, b1.y, b1.z, b1.w}};
#pragma unroll
      for (int ih = 0; ih < 2; ih++)
#pragma unroll
        for (int jh = 0; jh < 2; jh++)
#pragma unroll
          for (int il = 0; il < 4; il++)
#pragma unroll
            for (int jl = 0; jl < 4; jl++)
              acc[ih][jh][il][jl] = fmaf(av[ih][il], bv[jh][jl], acc[ih][jh][il][jl]);
    }
  }
  float* scb = sc + (size_t)b * HWn;
#pragma unroll
  for (int ih = 0; ih < 2; ih++)
#pragma unroll
    for (int il = 0; il < 4; il++) {
      int i = i0 + ih * 64 + ty * 4 + il;
#pragma unroll
      for (int jh = 0; jh < 2; jh++) {
        float4 st = make_float4(acc[ih][jh][il][0], acc[ih][jh][il][1],
                                acc[ih][jh][il][2], acc[ih][jh][il][3]);
        *(float4*)&scb[i * 256 + j0 + jh * 64 + tx * 4] = st;
      }
    }
}

__global__ __launch_bounds__(256) void softmax_kernel(float* __restrict__ at) {
  int wave = (blockIdx.x * 256 + threadIdx.x) >> 6;
  int lane = threadIdx.x & 63;
  float* row = at + (size_t)wave * 256;
  float v[4];
  float mm = -3.4e38f;
#pragma unroll
  for (int u = 0; u < 4; u++) {
    v[u] = row[lane + 64 * u];
    mm = fmaxf(mm, v[u]);
  }
#pragma unroll
  for (int o = 1; o < 64; o <<= 1) mm = fmaxf(mm, __shfl_xor(mm, o, 64));
  float s = 0.f;
#pragma unroll
  for (int u = 0; u < 4; u++) {
    v[u] = __expf(v[u] - mm);
    s += v[u];
  }
#pragma unroll
  for (int o = 1; o < 64; o <<= 1) s += __shfl_xor(s, o, 64);
  float inv = 1.0f / s;
#pragma unroll
  for (int u = 0; u < 4; u++) row[lane + 64 * u] = v[u] * inv;
}

__global__ __launch_bounds__(256, 2) void apply_kernel(
    const float* __restrict__ x, const float* __restrict__ at,
    const float* __restrict__ w3, const float* __restrict__ b3, float* __restrict__ out) {
  const int it = blockIdx.x, b = blockIdx.y;
  const int i0 = it * 16;
  const int t = threadIdx.x;
  __shared__ __align__(16) float pt[16 * 256];
  const float* atb = at + (size_t)b * HWn + i0 * 256;
#pragma unroll
  for (int e = 0; e < 4; e++)
    *(float4*)&pt[t * 4 + 1024 * e] = *(const float4*)&atb[t * 4 + 1024 * e];
  __syncthreads();
  float acc[8][16];
#pragma unroll
  for (int c = 0; c < 8; c++)
#pragma unroll
    for (int ii = 0; ii < 16; ii++) acc[c][ii] = 0.f;
  const float* xb = x + (size_t)b * CHWn + t;
  for (int j0 = 0; j0 < 256; j0 += 2) {
    float p2[16][2];
#pragma unroll
    for (int ii = 0; ii < 16; ii++) {
      float2 pp = *(const float2*)&pt[ii * 256 + j0];
      p2[ii][0] = pp.x;
      p2[ii][1] = pp.y;
    }
#pragma unroll
    for (int ju = 0; ju < 2; ju++) {
      float xv[8];
#pragma unroll
      for (int c = 0; c < 8; c++) xv[c] = xb[c * HWn + (j0 + ju) * 256];
#pragma unroll
      for (int c = 0; c < 8; c++)
#pragma unroll
        for (int ii = 0; ii < 16; ii++)
          acc[c][ii] = fmaf(xv[c], p2[ii][ju], acc[c][ii]);
    }
  }
#pragma unroll
  for (int co = 0; co < 8; co++) {
    float wr[8];
#pragma unroll
    for (int ci = 0; ci < 8; ci++) wr[ci] = w3[co * 8 + ci];
    float bb = b3[co];
#pragma unroll
    for (int ii = 0; ii < 16; ii++) {
      float o = bb;
#pragma unroll
      for (int ci = 0; ci < 8; ci++) o = fmaf(wr[ci], acc[ci][ii], o);
      out[(size_t)b * CHWn + co * HWn + (i0 + ii) * 256 + t] = o;
    }
  }
}

extern "C" void kernel_launch(void* const* d_in, const int* in_sizes, int n_in,
                              void* d_out, int out_size, void* d_ws, size_t ws_size,
                              hipStream_t stream) {
  const float* x  = (const float*)d_in[0];
  const float* w1 = (const float*)d_in[1];
  const float* b1 = (const float*)d_in[2];
  const float* w2 = (const float*)d_in[3];
  const float* b2 = (const float*)d_in[4];
  const float* w3 = (const float*)d_in[5];
  const float* b3 = (const float*)d_in[6];
  float* out = (float*)d_out;

  if (ws_size >= (size_t)92274688) {
    // fast path: vt 64MB | qh 8MB | kh 8MB | p 8MB
    char* wsb = (char*)d_ws;
    h16* vt = (h16*)wsb;
    h16* qh = (h16*)(wsb + 67108864);
    h16* kh = (h16*)(wsb + 75497472);
    h16* p  = (h16*)(wsb + 83886080);
    prep_kernel<<<dim3(8, 8, 64), dim3(256), 0, stream>>>(x, w1, b1, w2, b2, w3, b3, qh, kh, vt);
    scores_kernel<<<dim3(16, 64), dim3(256), 0, stream>>>(qh, kh, p);
    apply_kernel_v3<<<dim3(32, 64), dim3(256), 0, stream>>>(p, vt, out);
  } else {
    float* wsf = (float*)d_ws;
    float* q  = wsf;
    float* k  = wsf + 4194304;
    float* at = wsf + 8388608;
    qk_kernel<<<dim3(16384), dim3(256), 0, stream>>>(x, w1, b1, w2, b2, q, k);
    scores_kernel_f32<<<dim3(2, 2, 64), dim3(256), 0, stream>>>(q, k, at);
    softmax_kernel<<<dim3(4096), dim3(256), 0, stream>>>(at);
    apply_kernel<<<dim3(16, 64), dim3(256), 0, stream>>>(x, at, w3, b3, out);
  }
}